// Round 7
// baseline (472.445 us; speedup 1.0000x reference)
//
#include <hip/hip_runtime.h>
#include <hip/hip_bf16.h>
#include <cstdint>

#define TOKENS 8192
#define DIN    2048
#define UNITS  2048

#define BMT 256
#define BNT 256
#define BKS 64
#define NKSTEP (DIN / BKS)   // 32
#define NITER  (NKSTEP / 2)  // 16

typedef float  f32x4  __attribute__((ext_vector_type(4)));
typedef __bf16 bf16x8 __attribute__((ext_vector_type(8)));
typedef __attribute__((address_space(3))) unsigned char lds_byte_t;
typedef __attribute__((address_space(3))) unsigned int  lds_uint_t;
typedef const __attribute__((address_space(1))) unsigned int g_uint_t;

// LDS map: A: [buf][half] 16KB each at 0..64K; B: same at 64K..128K
#define A_OFF(buf, h) ((buf) * 32768 + (h) * 16384)
#define B_OFF(buf, c) (65536 + (buf) * 32768 + (c) * 16384)

__device__ __forceinline__ unsigned short f32_to_bf16_rne(float f) {
  unsigned int u = __float_as_uint(f);
  u += 0x7FFFu + ((u >> 16) & 1u);
  return (unsigned short)(u >> 16);
}

__device__ __forceinline__ bf16x8 ds_read_b128f(uint32_t addr) {
  bf16x8 r;
  asm volatile("ds_read_b128 %0, %1" : "=v"(r) : "v"(addr));
  return r;
}

// ---- kernel 1: x fp32 -> bf16 (RNE) ----
__global__ void cvt_x_kernel(const float* __restrict__ x,
                             unsigned short* __restrict__ xb, int n4) {
  int i = blockIdx.x * blockDim.x + threadIdx.x;
  const int stride = gridDim.x * blockDim.x;
  for (; i < n4; i += stride) {
    const float4 v = reinterpret_cast<const float4*>(x)[i];
    ushort4 o;
    o.x = f32_to_bf16_rne(v.x);
    o.y = f32_to_bf16_rne(v.y);
    o.z = f32_to_bf16_rne(v.z);
    o.w = f32_to_bf16_rne(v.w);
    reinterpret_cast<ushort4*>(xb)[i] = o;
  }
}

// ---- kernel 2: Wt[u][k] = sign(W[k][u]) bf16 +/-1 ----
__global__ void sign_transpose_kernel(const float* __restrict__ W,
                                      unsigned short* __restrict__ Wt) {
  __shared__ unsigned short tile[32][33];
  const int u0 = blockIdx.x * 32;
  const int k0 = blockIdx.y * 32;
  const int tx = threadIdx.x;
  const int ty = threadIdx.y;
#pragma unroll
  for (int j = 0; j < 32; j += 8) {
    const float w = W[(size_t)(k0 + ty + j) * UNITS + u0 + tx];
    tile[tx][ty + j] = (w >= 0.0f) ? (unsigned short)0x3F80u
                                   : (unsigned short)0xBF80u;
  }
  __syncthreads();
#pragma unroll
  for (int j = 0; j < 32; j += 8)
    Wt[(size_t)(u0 + ty + j) * DIN + k0 + tx] = tile[ty + j][tx];
}

// ---- kernel 3: 256x256 8-phase bf16 MFMA GEMM, read-ahead-1 pipelined ----
// Phase P issues ds_reads for phase P+1's fragments, then lgkmcnt(k=just
// issued) -> drains only phase P's fragments (loaded last phase, completed
// under last phase's MFMA). New reads drain under THIS phase's MFMA.
__global__ __launch_bounds__(512, 2) void gemm8_kernel(
    const unsigned short* __restrict__ A,
    const unsigned short* __restrict__ Bt,
    float* __restrict__ C) {
  extern __shared__ char smem_raw[];
  lds_byte_t* sm = (lds_byte_t*)smem_raw;
  const uint32_t smbase = (uint32_t)(uintptr_t)sm;

  const int tid  = threadIdx.x;
  const int lane = tid & 63;
  const int w    = tid >> 6;   // 0..7
  const int wr   = w >> 2;     // 0..1 (M half of wave grid)
  const int wc   = w & 3;      // 0..3 (N quarter)
  const int l15  = lane & 15;
  const int l4   = lane >> 4;  // 0..3
  const int ln8  = lane >> 3;  // 0..7
  const int la7  = lane & 7;

  // bijective XCD swizzle: nwg=256, q=32
  const int bid  = blockIdx.x;
  const int swzb = (bid & 7) * 32 + (bid >> 3);
  const int tm = swzb >> 3, tn = swzb & 7;   // 32 x 8 tiles
  const int m0 = tm * BMT, n0 = tn * BNT;

  // staging: lane -> row w*8+ln8, 16B phys slot la7; source col pre-swizzled
  const int stg_colel = ((la7 ^ ln8) << 3);   // element offset in K-step
  const int stg_lds   = w * 1024 + lane * 16; // + n*8192 per call

  // reads: phys in-row byte = (s*64 + l4*16) ^ ((row&7)<<4), row&7 == la7
  const int xsw   = la7 << 4;
  const int koff0 = (0 * 64 + l4 * 16) ^ xsw;
  const int koff1 = (1 * 64 + l4 * 16) ^ xsw;
  const uint32_t a_rb = (uint32_t)(wr * 64 + l15) * 128;  // + i*2048 + koff
  const uint32_t b_rb = (uint32_t)(wc * 32 + l15) * 128;  // + jj*2048 + koff

  // double fragment sets (read-ahead-1)
  bf16x8 AfA[4][2], AfB[4][2], BfA[2][2], BfB[2][2];
  f32x4 acc[2][4][2][2];
#pragma unroll
  for (int h = 0; h < 2; ++h)
#pragma unroll
    for (int i = 0; i < 4; ++i)
#pragma unroll
      for (int c = 0; c < 2; ++c)
#pragma unroll
        for (int j = 0; j < 2; ++j)
#pragma unroll
          for (int r = 0; r < 4; ++r) acc[h][i][c][j][r] = 0.0f;

#define LGKM(n) asm volatile("s_waitcnt lgkmcnt(" #n ")" ::: "memory")
#define VMC(n)  asm volatile("s_waitcnt vmcnt(" #n ")" ::: "memory")
#define SB0     __builtin_amdgcn_sched_barrier(0)
#define BAR     __builtin_amdgcn_s_barrier()

#define STAGE_A(buf, h, ks) do { \
    _Pragma("unroll") for (int n_ = 0; n_ < 2; ++n_) { \
      const size_t gr_ = (size_t)(m0 + (h) * 128 + n_ * 64 + w * 8 + ln8) * DIN \
                         + (size_t)(ks) * 64 + stg_colel; \
      __builtin_amdgcn_global_load_lds((g_uint_t*)(const void*)(A + gr_), \
          (lds_uint_t*)(sm + A_OFF(buf, (h)) + n_ * 8192 + stg_lds), 16, 0, 0); \
    } } while (0)

#define STAGE_B(buf, c, ks) do { \
    _Pragma("unroll") for (int n_ = 0; n_ < 2; ++n_) { \
      const size_t gr_ = (size_t)(n0 + (c) * 128 + n_ * 64 + w * 8 + ln8) * DIN \
                         + (size_t)(ks) * 64 + stg_colel; \
      __builtin_amdgcn_global_load_lds((g_uint_t*)(const void*)(Bt + gr_), \
          (lds_uint_t*)(sm + B_OFF(buf, (c)) + n_ * 8192 + stg_lds), 16, 0, 0); \
    } } while (0)

#define RD_A(SET, buf, h) do { _Pragma("unroll") for (int i_ = 0; i_ < 4; ++i_) { \
    SET[i_][0] = ds_read_b128f(smbase + A_OFF(buf, h) + a_rb + i_ * 2048 + koff0); \
    SET[i_][1] = ds_read_b128f(smbase + A_OFF(buf, h) + a_rb + i_ * 2048 + koff1); } } while (0)

#define RD_B(SET, buf, c) do { _Pragma("unroll") for (int j_ = 0; j_ < 2; ++j_) { \
    SET[j_][0] = ds_read_b128f(smbase + B_OFF(buf, c) + b_rb + j_ * 2048 + koff0); \
    SET[j_][1] = ds_read_b128f(smbase + B_OFF(buf, c) + b_rb + j_ * 2048 + koff1); } } while (0)

#define MM(h, c, ASET, BSET) do { \
  __builtin_amdgcn_s_setprio(1); \
  _Pragma("unroll") for (int i_ = 0; i_ < 4; ++i_) \
  _Pragma("unroll") for (int j_ = 0; j_ < 2; ++j_) { \
    acc[h][i_][c][j_] = __builtin_amdgcn_mfma_f32_16x16x32_bf16( \
        ASET[i_][0], BSET[j_][0], acc[h][i_][c][j_], 0, 0, 0); \
    acc[h][i_][c][j_] = __builtin_amdgcn_mfma_f32_16x16x32_bf16( \
        ASET[i_][1], BSET[j_][1], acc[h][i_][c][j_], 0, 0, 0); } \
  __builtin_amdgcn_s_setprio(0); } while (0)

  // prologue: stage buf0(k0) then buf1(k1); drain buf0; preload P1 frags
  STAGE_A(0, 0, 0); STAGE_B(0, 1, 0); STAGE_B(0, 0, 0); STAGE_A(0, 1, 0);
  STAGE_A(1, 0, 1); STAGE_B(1, 1, 1); STAGE_B(1, 0, 1); STAGE_A(1, 1, 1);
  VMC(8);
  BAR;
  RD_A(AfA, 0, 0); RD_B(BfA, 0, 0);  // fragments for P1

  // steady loop (j = 0..NITER-2); consumption walk:
  // P1:(A00,B00) P2:(A00,B01) P3:(A01,B01) P4:(A01,B00)
  // P5:(A10,B10) P6:(A10,B11) P7:(A11,B11) P8:(A11,B10)
  for (int j = 0; j < NITER - 1; ++j) {
    const int k2 = 2 * j + 2, k3 = 2 * j + 3;
    // P1: rd B01->BfB (for P2)
    RD_B(BfB, 0, 1); LGKM(4);  SB0; STAGE_A(0, 0, k2); MM(0, 0, AfA, BfA);            BAR;
    // P2: rd A01->AfB (for P3)
    RD_A(AfB, 0, 1); LGKM(8);  SB0; STAGE_B(0, 1, k2); MM(0, 1, AfA, BfB);            BAR;
    // P3: no rd (P4 reuses AfB,BfA)
                     LGKM(0);  SB0; STAGE_B(0, 0, k2); MM(1, 1, AfB, BfB); VMC(6);    BAR;
    // P4: rd A10->AfA, B10->BfB (for P5)
    RD_A(AfA, 1, 0);
    RD_B(BfB, 1, 0); LGKM(12); SB0; STAGE_A(0, 1, k2); MM(1, 0, AfB, BfA);            BAR;
    // P5: rd B11->BfA (for P6)
    RD_B(BfA, 1, 1); LGKM(4);  SB0; STAGE_A(1, 0, k3); MM(0, 0, AfA, BfB); VMC(8);    BAR;
    // P6: rd A11->AfB (for P7)
    RD_A(AfB, 1, 1); LGKM(8);  SB0; STAGE_B(1, 1, k3); MM(0, 1, AfA, BfA);            BAR;
    // P7: no rd (P8 reuses AfB,BfB)
                     LGKM(0);  SB0; STAGE_B(1, 0, k3); MM(1, 1, AfB, BfA); VMC(6);    BAR;
    // P8: rd A00',B00' (buf0, k2 data) for next iter's P1
    RD_A(AfA, 0, 0);
    RD_B(BfA, 0, 0); LGKM(12); SB0; STAGE_A(1, 1, k3); MM(1, 0, AfB, BfB); VMC(8);    BAR;
  }

  // peeled last iteration (no stages; tail-exact vmcnt)
  RD_B(BfB, 0, 1); LGKM(4);  SB0; MM(0, 0, AfA, BfA);            BAR;
  RD_A(AfB, 0, 1); LGKM(8);  SB0; MM(0, 1, AfA, BfB);            BAR;
                   LGKM(0);  SB0; MM(1, 1, AfB, BfB); VMC(2);    BAR;
  RD_A(AfA, 1, 0);
  RD_B(BfB, 1, 0); LGKM(12); SB0; MM(1, 0, AfB, BfA);            BAR;
  RD_B(BfA, 1, 1); LGKM(4);  SB0; MM(0, 0, AfA, BfB); VMC(0);    BAR;
  RD_A(AfB, 1, 1); LGKM(8);  SB0; MM(0, 1, AfA, BfA);            BAR;
                   LGKM(0);  SB0; MM(1, 1, AfB, BfA);            BAR;
                   LGKM(0);  SB0; MM(1, 0, AfB, BfB);

  // epilogue: C/D layout col=lane&15, row=(lane>>4)*4+r
#pragma unroll
  for (int h = 0; h < 2; ++h)
#pragma unroll
    for (int cc = 0; cc < 2; ++cc)
#pragma unroll
      for (int i = 0; i < 4; ++i)
#pragma unroll
        for (int jj = 0; jj < 2; ++jj)
#pragma unroll
          for (int r = 0; r < 4; ++r) {
            const int row = m0 + h * 128 + wr * 64 + i * 16 + l4 * 4 + r;
            const int col = n0 + cc * 128 + wc * 32 + jj * 16 + l15;
            C[(size_t)row * UNITS + col] = acc[h][i][cc][jj][r];
          }
#undef STAGE_A
#undef STAGE_B
#undef RD_A
#undef RD_B
#undef MM
#undef LGKM
#undef VMC
#undef SB0
#undef BAR
}

extern "C" void kernel_launch(void* const* d_in, const int* in_sizes, int n_in,
                              void* d_out, int out_size, void* d_ws, size_t ws_size,
                              hipStream_t stream) {
  const float* x = (const float*)d_in[0];
  const float* W = (const float*)d_in[1];
  float* out = (float*)d_out;

  unsigned short* xb = (unsigned short*)d_ws;       // 32 MB
  unsigned short* Wt = xb + (size_t)TOKENS * DIN;   // 8 MB

  cvt_x_kernel<<<2048, 256, 0, stream>>>(x, xb, TOKENS * DIN / 4);

  dim3 gT(UNITS / 32, DIN / 32), bT(32, 8);
  sign_transpose_kernel<<<gT, bT, 0, stream>>>(W, Wt);

  (void)hipFuncSetAttribute((const void*)gemm8_kernel,
                            hipFuncAttributeMaxDynamicSharedMemorySize, 131072);
  const int grid = (TOKENS / BMT) * (UNITS / BNT);  // 256
  gemm8_kernel<<<grid, 512, 131072, stream>>>(xb, Wt, out);
}

// Round 8
// 177.685 us; speedup vs baseline: 2.6589x; 2.6589x over previous
//
#include <hip/hip_runtime.h>
#include <hip/hip_bf16.h>
#include <cstdint>

#define TOKENS 8192
#define DIN    2048
#define UNITS  2048

#define BMT 256
#define BNT 256
#define BKS 64
#define NKSTEP (DIN / BKS)   // 32
#define NITER  (NKSTEP / 2)  // 16

typedef float  f32x4  __attribute__((ext_vector_type(4)));
typedef __bf16 bf16x8 __attribute__((ext_vector_type(8)));
typedef __attribute__((address_space(3))) unsigned char lds_byte_t;
typedef __attribute__((address_space(3))) unsigned int  lds_uint_t;
typedef const __attribute__((address_space(1))) unsigned int g_uint_t;

// LDS map: A: [buf][half] 16KB each at 0..64K; B: same at 64K..128K
#define A_OFF(buf, h) ((buf) * 32768 + (h) * 16384)
#define B_OFF(buf, c) (65536 + (buf) * 32768 + (c) * 16384)

__device__ __forceinline__ unsigned short f32_to_bf16_rne(float f) {
  unsigned int u = __float_as_uint(f);
  u += 0x7FFFu + ((u >> 16) & 1u);
  return (unsigned short)(u >> 16);
}

// normal (compiler-scheduled) LDS vector load -> ds_read_b128 with
// compiler-managed progressive lgkmcnt draining
__device__ __forceinline__ bf16x8 lds_ld(const lds_byte_t* p) {
  return *(const __attribute__((address_space(3))) bf16x8*)p;
}

// ---- kernel 1: fused prep: x fp32->bf16  +  Wt[u][k]=sign(W[k][u]) ----
__global__ __launch_bounds__(256) void prep_kernel(
    const float* __restrict__ x, unsigned short* __restrict__ xb,
    const float* __restrict__ W, unsigned short* __restrict__ Wt) {
  __shared__ unsigned short tile[32][33];
  const int tid = threadIdx.x;
  if (blockIdx.x < 2048) {
    // cvt: grid-stride over 4M float4
    const int stride = 2048 * 256;
    for (int i = blockIdx.x * 256 + tid; i < TOKENS * DIN / 4; i += stride) {
      const float4 v = reinterpret_cast<const float4*>(x)[i];
      ushort4 o;
      o.x = f32_to_bf16_rne(v.x);
      o.y = f32_to_bf16_rne(v.y);
      o.z = f32_to_bf16_rne(v.z);
      o.w = f32_to_bf16_rne(v.w);
      reinterpret_cast<ushort4*>(xb)[i] = o;
    }
  } else {
    // sign+transpose: 4096 blocks of 32x32 tiles
    const int b  = blockIdx.x - 2048;
    const int u0 = (b & 63) * 32;
    const int k0 = (b >> 6) * 32;
    const int tx = tid & 31;
    const int ty = tid >> 5;  // 0..7
#pragma unroll
    for (int j = 0; j < 32; j += 8) {
      const float w = W[(size_t)(k0 + ty + j) * UNITS + u0 + tx];
      tile[tx][ty + j] = (w >= 0.0f) ? (unsigned short)0x3F80u
                                     : (unsigned short)0xBF80u;
    }
    __syncthreads();
#pragma unroll
    for (int j = 0; j < 32; j += 8)
      Wt[(size_t)(u0 + ty + j) * DIN + k0 + tx] = tile[ty + j][tx];
  }
}

// ---- kernel 2: 256x256 8-phase bf16 MFMA GEMM, compiler-scheduled reads ----
// Per phase: {AS(3) vector loads | stage | MFMA (compiler interleaves
// progressive lgkmcnt)} ... vmcnt(6)@P4/P8 ... sched_barrier(0); s_barrier.
__global__ __launch_bounds__(512, 2) void gemm8_kernel(
    const unsigned short* __restrict__ A,
    const unsigned short* __restrict__ Bt,
    float* __restrict__ C) {
  extern __shared__ char smem_raw[];
  lds_byte_t* sm = (lds_byte_t*)smem_raw;

  const int tid  = threadIdx.x;
  const int lane = tid & 63;
  const int w    = tid >> 6;   // 0..7
  const int wr   = w >> 2;     // 0..1 (M half of wave grid)
  const int wc   = w & 3;      // 0..3 (N quarter)
  const int l15  = lane & 15;
  const int l4   = lane >> 4;  // 0..3
  const int ln8  = lane >> 3;  // 0..7
  const int la7  = lane & 7;

  // bijective XCD swizzle: nwg=256, q=32
  const int bid  = blockIdx.x;
  const int swzb = (bid & 7) * 32 + (bid >> 3);
  const int tm = swzb >> 3, tn = swzb & 7;   // 32 x 8 tiles
  const int m0 = tm * BMT, n0 = tn * BNT;

  // staging: lane -> row w*8+ln8, 16B phys slot la7; source col pre-swizzled
  const int stg_colel = ((la7 ^ ln8) << 3);   // element offset in K-step
  const int stg_lds   = w * 1024 + lane * 16; // + n*8192 per call

  // reads: phys in-row byte = (s*64 + l4*16) ^ ((row&7)<<4), row&7 == la7
  const int xsw   = la7 << 4;
  const int koff0 = (0 * 64 + l4 * 16) ^ xsw;
  const int koff1 = (1 * 64 + l4 * 16) ^ xsw;
  const uint32_t a_rb = (uint32_t)(wr * 64 + l15) * 128;  // + i*2048 + koff
  const uint32_t b_rb = (uint32_t)(wc * 32 + l15) * 128;  // + jj*2048 + koff

  // fragments: single A set, double-buffered B (Bf=B*0, Bf2=B*1)
  bf16x8 Af[4][2], Bf[2][2], Bf2[2][2];
  f32x4 acc[2][4][2][2];
#pragma unroll
  for (int h = 0; h < 2; ++h)
#pragma unroll
    for (int i = 0; i < 4; ++i)
#pragma unroll
      for (int c = 0; c < 2; ++c)
#pragma unroll
        for (int j = 0; j < 2; ++j)
#pragma unroll
          for (int r = 0; r < 4; ++r) acc[h][i][c][j][r] = 0.0f;

#define VMC0    asm volatile("s_waitcnt vmcnt(0)" ::: "memory")
#define VMC6    asm volatile("s_waitcnt vmcnt(6)" ::: "memory")
#define SB0     __builtin_amdgcn_sched_barrier(0)
#define BAR     __builtin_amdgcn_s_barrier()

#define STAGE_A(buf, h, ks) do { if ((ks) < NKSTEP) { \
    _Pragma("unroll") for (int n_ = 0; n_ < 2; ++n_) { \
      const size_t gr_ = (size_t)(m0 + (h) * 128 + n_ * 64 + w * 8 + ln8) * DIN \
                         + (size_t)(ks) * 64 + stg_colel; \
      __builtin_amdgcn_global_load_lds((g_uint_t*)(const void*)(A + gr_), \
          (lds_uint_t*)(sm + A_OFF(buf, (h)) + n_ * 8192 + stg_lds), 16, 0, 0); \
    } } } while (0)

#define STAGE_B(buf, c, ks) do { if ((ks) < NKSTEP) { \
    _Pragma("unroll") for (int n_ = 0; n_ < 2; ++n_) { \
      const size_t gr_ = (size_t)(n0 + (c) * 128 + n_ * 64 + w * 8 + ln8) * DIN \
                         + (size_t)(ks) * 64 + stg_colel; \
      __builtin_amdgcn_global_load_lds((g_uint_t*)(const void*)(Bt + gr_), \
          (lds_uint_t*)(sm + B_OFF(buf, (c)) + n_ * 8192 + stg_lds), 16, 0, 0); \
    } } } while (0)

#define RD_A(buf, h) do { _Pragma("unroll") for (int i_ = 0; i_ < 4; ++i_) { \
    Af[i_][0] = lds_ld(sm + A_OFF(buf, h) + a_rb + i_ * 2048 + koff0); \
    Af[i_][1] = lds_ld(sm + A_OFF(buf, h) + a_rb + i_ * 2048 + koff1); } } while (0)

#define RD_B(SET, buf, c) do { _Pragma("unroll") for (int j_ = 0; j_ < 2; ++j_) { \
    SET[j_][0] = lds_ld(sm + B_OFF(buf, c) + b_rb + j_ * 2048 + koff0); \
    SET[j_][1] = lds_ld(sm + B_OFF(buf, c) + b_rb + j_ * 2048 + koff1); } } while (0)

#define MM(h, c, BSET) do { \
  __builtin_amdgcn_s_setprio(1); \
  _Pragma("unroll") for (int i_ = 0; i_ < 4; ++i_) \
  _Pragma("unroll") for (int j_ = 0; j_ < 2; ++j_) { \
    acc[h][i_][c][j_] = __builtin_amdgcn_mfma_f32_16x16x32_bf16( \
        Af[i_][0], BSET[j_][0], acc[h][i_][c][j_], 0, 0, 0); \
    acc[h][i_][c][j_] = __builtin_amdgcn_mfma_f32_16x16x32_bf16( \
        Af[i_][1], BSET[j_][1], acc[h][i_][c][j_], 0, 0, 0); } \
  __builtin_amdgcn_s_setprio(0); } while (0)

  // prologue: buf0 <- k0 (8 loads, oldest), then buf1 <- k1
  STAGE_A(0, 0, 0); STAGE_B(0, 1, 0); STAGE_B(0, 0, 0); STAGE_A(0, 1, 0);
  STAGE_A(1, 0, 1); STAGE_B(1, 1, 1); STAGE_B(1, 0, 1); STAGE_A(1, 1, 1);
  asm volatile("s_waitcnt vmcnt(8)" ::: "memory");  // drains buf0's 8
  BAR;

  for (int j = 0; j < NITER; ++j) {
    const int k1 = 2 * j + 1, k2 = 2 * j + 2, k3 = 2 * j + 3;
    const bool last = (j == NITER - 1);
    // buf0, c-first walk: (h0,c0) (h0,c1) (h1,c1) (h1,c0)
    // P1: read A00,B00; stage B10<-k1 (consumed at P5 of NEXT... see R6 liveness)
    RD_A(0, 0); RD_B(Bf, 0, 0); STAGE_B(1, 0, k1); MM(0, 0, Bf);
    SB0; BAR;
    // P2: read B01; stage A00<-k2
    RD_B(Bf2, 0, 1); STAGE_A(0, 0, k2); MM(0, 1, Bf2);
    SB0; BAR;
    // P3: read A01; stage B01<-k2
    RD_A(0, 1); STAGE_B(0, 1, k2); MM(1, 1, Bf2);
    SB0; BAR;
    // P4: no reads; stage A01<-k2; vmcnt checkpoint
    STAGE_A(0, 1, k2); MM(1, 0, Bf);
    if (last) { VMC0; } else { VMC6; }
    SB0; BAR;
    // buf1
    // P5: read A10,B10; stage B00<-k2
    RD_A(1, 0); RD_B(Bf, 1, 0); STAGE_B(0, 0, k2); MM(0, 0, Bf);
    SB0; BAR;
    // P6: read B11; stage A10<-k3
    RD_B(Bf2, 1, 1); STAGE_A(1, 0, k3); MM(0, 1, Bf2);
    SB0; BAR;
    // P7: read A11; stage B11<-k3
    RD_A(1, 1); STAGE_B(1, 1, k3); MM(1, 1, Bf2);
    SB0; BAR;
    // P8: no reads; stage A11<-k3; vmcnt checkpoint
    STAGE_A(1, 1, k3); MM(1, 0, Bf);
    if (!last) { VMC6; }
    SB0; BAR;
  }

  // epilogue: C/D layout col=lane&15, row=(lane>>4)*4+r
#pragma unroll
  for (int h = 0; h < 2; ++h)
#pragma unroll
    for (int cc = 0; cc < 2; ++cc)
#pragma unroll
      for (int i = 0; i < 4; ++i)
#pragma unroll
        for (int jj = 0; jj < 2; ++jj)
#pragma unroll
          for (int r = 0; r < 4; ++r) {
            const int row = m0 + h * 128 + wr * 64 + i * 16 + l4 * 4 + r;
            const int col = n0 + cc * 128 + wc * 32 + jj * 16 + l15;
            C[(size_t)row * UNITS + col] = acc[h][i][cc][jj][r];
          }
#undef STAGE_A
#undef STAGE_B
#undef RD_A
#undef RD_B
#undef MM
#undef VMC0
#undef VMC6
#undef SB0
#undef BAR
}

extern "C" void kernel_launch(void* const* d_in, const int* in_sizes, int n_in,
                              void* d_out, int out_size, void* d_ws, size_t ws_size,
                              hipStream_t stream) {
  const float* x = (const float*)d_in[0];
  const float* W = (const float*)d_in[1];
  float* out = (float*)d_out;

  unsigned short* xb = (unsigned short*)d_ws;       // 32 MB
  unsigned short* Wt = xb + (size_t)TOKENS * DIN;   // 8 MB

  prep_kernel<<<2048 + 4096, 256, 0, stream>>>(x, xb, W, Wt);

  (void)hipFuncSetAttribute((const void*)gemm8_kernel,
                            hipFuncAttributeMaxDynamicSharedMemorySize, 131072);
  const int grid = (TOKENS / BMT) * (UNITS / BNT);  // 256
  gemm8_kernel<<<grid, 512, 131072, stream>>>(xb, Wt, out);
}